// Round 13
// baseline (4215.675 us; speedup 1.0000x reference)
//
#include <hip/hip_runtime.h>

// ---------------------------------------------------------------------------
// MTSLTM (time-aware LSTM), B=64 T=512 D=256 H=512 — round 13: dual-stream.
// Persistent kernel: 32 blocks x 512 threads (8 waves), 1 block/CU.
// Grid: 2 group-pairs (p=bid&1) x 16 col-slices (cs=bid>>1, 32 h-cols).
// Each block runs TWO interleaved recurrences (stream 0: batches p*32..+15,
// stream 1: p*32+16..+31) sharing the same weight registers. While stream S
// computes (GEMM+cell), stream S'^'s exchange data propagates through L3 and
// its speculative load flies -> near-100% spec hit, no fallback round trip.
// Exchange protocol: r11/r12-proven agent-scope sc1 + epoch-tagged words
// ((h<<16)|c, tag ((t>>1)&1)<<14 in c's free bit14), subflag fallback.
// h/c/g5/s5 LDS time-shared between streams (barrier-separated lifetimes);
// x_lds duplicated per stream. All barriers lgkm-only; slow VMEM (out store,
// x prefetch, tdel) issues in phase 2 only (r12's vmcnt-poison fix).
// ---------------------------------------------------------------------------

constexpr int kB = 64, kT = 512, kD = 256, kH = 512, kG = 2048;
constexpr int NBLK = 32, NTHR = 512;

typedef __attribute__((ext_vector_type(8))) short short8v;   // 8 bf16
typedef __attribute__((ext_vector_type(4))) float f32x4;
typedef __attribute__((ext_vector_type(4))) unsigned int uint4v;

__device__ __forceinline__ float fsig(float x)  { return 1.0f / (1.0f + __expf(-x)); }
__device__ __forceinline__ float ftanh(float x) { return 2.0f / (1.0f + __expf(-2.0f * x)) - 1.0f; }
__device__ __forceinline__ unsigned short f2bf(float f) {    // RNE f32->bf16
  unsigned u = __float_as_uint(f);
  return (unsigned short)((u + 0x7FFFu + ((u >> 16) & 1u)) >> 16);
}

#define LGKM_BARRIER() asm volatile("s_waitcnt lgkmcnt(0)\n\ts_barrier" ::: "memory")

__global__ __launch_bounds__(NTHR, 1) void mtsltm_kernel(
    const float* __restrict__ inp, const float* __restrict__ tdel,
    const float* __restrict__ Wd,  const float* __restrict__ W,
    const float* __restrict__ U,   const float* __restrict__ bias,
    float* __restrict__ out,
    unsigned* __restrict__ hc, unsigned* __restrict__ flags)
{
  // 68.5 KB LDS. h/c/x XOR-swizzled in 16B units (unit' = unit ^ (row&7)).
  // h_lds/c_lds/g5/s5 are TIME-SHARED by the two streams (barrier-separated).
  __shared__ __align__(16) unsigned short h_lds[16][512];     // 16 KB
  __shared__ __align__(16) unsigned short c_lds[16][512];     // 16 KB
  __shared__ __align__(16) unsigned short x_lds[2][16][256];  // 16 KB
  __shared__ float g5[8][320];   // gate tiles, stride-5 (conflict-free)
  __shared__ float s5[8][320];   // Wd partials, stride-5

  const int tid = threadIdx.x, bid = blockIdx.x;
  const int p  = bid & 1;          // group-pair: batches p*32 .. p*32+31
  const int cs = bid >> 1;         // col slice [0,16): h-cols cs*32..cs*32+32
  const int wv = tid >> 6, ln = tid & 63;
  const int lm = ln & 15, lg = ln >> 4;   // MFMA lane decomposition

  // ---------------- one-time: weights -> VGPRs (bf16 B-fragments) -----------
  const int gcol = (wv >> 1) * kH + cs * 32 + (wv & 1) * 16 + lm;
  short8v bU[16];                                   // U[512][gcol]
  #pragma unroll
  for (int kt = 0; kt < 16; ++kt) {
    short8v v;
    #pragma unroll
    for (int e = 0; e < 8; ++e)
      v[e] = (short)f2bf(U[(size_t)(kt * 32 + lg * 8 + e) * kG + gcol]);
    bU[kt] = v;
  }
  short8v bX[8];                                    // W[256][gcol]
  #pragma unroll
  for (int kt = 0; kt < 8; ++kt) {
    short8v v;
    #pragma unroll
    for (int e = 0; e < 8; ++e)
      v[e] = (short)f2bf(W[(size_t)(kt * 32 + lg * 8 + e) * kG + gcol]);
    bX[kt] = v;
  }
  const int kq = wv >> 1, ns = wv & 1;   // Wd: k-quarter kq, n-tile ns
  short8v bWd[4];
  #pragma unroll
  for (int kt = 0; kt < 4; ++kt) {
    short8v v;
    #pragma unroll
    for (int e = 0; e < 8; ++e)
      v[e] = (short)f2bf(Wd[(size_t)(kq * 128 + kt * 32 + lg * 8 + e) * kH
                            + cs * 32 + ns * 16 + lm]);
    bWd[kt] = v;
  }
  const float bias_r = bias[gcol];

  // ---------------- identities ----------------
  const int r = tid & 15, ch = tid >> 4, rs = r & 7;   // x staging
  const int row2 = ln >> 2, q = ln & 3;                // hc staging (per wave)
  const int cm = tid >> 5, cj = tid & 31;              // cell: batch cm, col cj
  const int lidx = ((cm >> 2) << 4) | (cj & 15), jr = cm & 3, chf = cj >> 4;
  const int colg = cs * 32 + cj;
  const int base0 = p * 32, base1 = p * 32 + 16;       // stream batch bases
  const size_t HID = (size_t)kB * kT * kH;

  // per-stream state (named scalars -> registers)
  float ck0 = 0.f, ck1 = 0.f, oh0 = 0.f, oh1 = 0.f;
  float4 xa0, xb0, xa1, xb1;
  uint4v wA0{}, wA1{}, wA2{}, wA3{};   // in-flight spec for stream 0
  uint4v wB0{}, wB1{}, wB2{}, wB3{};   // in-flight spec for stream 1

  // ---------------- half-step (phases 1-3 for one stream) -------------------
  auto half = [&](int T, int SID, int BASE, int OBASE, int OT,
                  unsigned short (&XL)[16][256],
                  float& ckeep, float& ohold, float& tdvr,
                  float4& xar, float4& xbr,
                  uint4v& w0, uint4v& w1, uint4v& w2, uint4v& w3,
                  uint4v& n0, uint4v& n1, uint4v& n2, uint4v& n3) {
    // ===== phase 1: xgemm in spec-load shadow, validate, land h/c ==========
    f32x4 xacc = {bias_r, bias_r, bias_r, bias_r};
    #pragma unroll
    for (int kt = 0; kt < 8; ++kt) {
      short8v av = *(const short8v*)&XL[lm][((kt * 4 + lg) ^ (lm & 7)) * 8];
      xacc = __builtin_amdgcn_mfma_f32_16x16x32_bf16(av, bX[kt], xacc, 0, 0, 0);
    }
    if (T > 0) {
      asm volatile("s_waitcnt vmcnt(0)" ::: "memory");
      __builtin_amdgcn_sched_barrier(0);
      const unsigned ep = (((unsigned)(T - 1) >> 1) & 1u) << 14;
      const unsigned* srcm = hc + ((size_t)((T - 1) & 1) * kB + BASE + row2) * kH
                                + 64 * wv + 16 * q;
      unsigned bad = (w0.x ^ ep) | (w0.y ^ ep) | (w0.z ^ ep) | (w0.w ^ ep)
                   | (w1.x ^ ep) | (w1.y ^ ep) | (w1.z ^ ep) | (w1.w ^ ep)
                   | (w2.x ^ ep) | (w2.y ^ ep) | (w2.z ^ ep) | (w2.w ^ ep)
                   | (w3.x ^ ep) | (w3.y ^ ep) | (w3.z ^ ep) | (w3.w ^ ep);
      if (!__all((bad & 0x4000u) == 0u)) {
        // fallback: poll the 16 sub-flags of my 2 producers, then reload
        const unsigned* fp = flags +
            (size_t)(((((2 * wv + (ln >> 3)) * 2 + p) * 2 + SID) * 8) + (ln & 7)) * 32;
        int spins = 0;
        for (;;) {
          unsigned v = 0xFFFFFFFFu;
          if (ln < 16)
            asm volatile("global_load_dword %0, %1, off sc1\n\ts_waitcnt vmcnt(0)"
                         : "=&v"(v) : "v"(fp) : "memory");
          if (__all(v >= (unsigned)T)) break;
          if (++spins > (1 << 20)) break;   // safety valve
        }
        for (int vt = 0; vt < 4096; ++vt) {
          asm volatile(
            "global_load_dwordx4 %0, %4, off sc1\n\t"
            "global_load_dwordx4 %1, %4, off offset:16 sc1\n\t"
            "global_load_dwordx4 %2, %4, off offset:32 sc1\n\t"
            "global_load_dwordx4 %3, %4, off offset:48 sc1\n\t"
            "s_waitcnt vmcnt(0)"
            : "=&v"(w0), "=&v"(w1), "=&v"(w2), "=&v"(w3)
            : "v"(srcm) : "memory");
          __builtin_amdgcn_sched_barrier(0);
          bad = (w0.x ^ ep) | (w0.y ^ ep) | (w0.z ^ ep) | (w0.w ^ ep)
              | (w1.x ^ ep) | (w1.y ^ ep) | (w1.z ^ ep) | (w1.w ^ ep)
              | (w2.x ^ ep) | (w2.y ^ ep) | (w2.z ^ ep) | (w2.w ^ ep)
              | (w3.x ^ ep) | (w3.y ^ ep) | (w3.z ^ ep) | (w3.w ^ ep);
          if (__all((bad & 0x4000u) == 0u)) break;
        }
      }
      // unpack: word = (h<<16) | c (bit14 = epoch tag, masked off)
      uint4v hA, hB, cA, cB;
      hA.x = (w0.x >> 16) | (w0.y & 0xFFFF0000u);
      hA.y = (w0.z >> 16) | (w0.w & 0xFFFF0000u);
      hA.z = (w1.x >> 16) | (w1.y & 0xFFFF0000u);
      hA.w = (w1.z >> 16) | (w1.w & 0xFFFF0000u);
      hB.x = (w2.x >> 16) | (w2.y & 0xFFFF0000u);
      hB.y = (w2.z >> 16) | (w2.w & 0xFFFF0000u);
      hB.z = (w3.x >> 16) | (w3.y & 0xFFFF0000u);
      hB.w = (w3.z >> 16) | (w3.w & 0xFFFF0000u);
      cA.x = (w0.x & 0xBFFFu) | ((w0.y & 0xBFFFu) << 16);
      cA.y = (w0.z & 0xBFFFu) | ((w0.w & 0xBFFFu) << 16);
      cA.z = (w1.x & 0xBFFFu) | ((w1.y & 0xBFFFu) << 16);
      cA.w = (w1.z & 0xBFFFu) | ((w1.w & 0xBFFFu) << 16);
      cB.x = (w2.x & 0xBFFFu) | ((w2.y & 0xBFFFu) << 16);
      cB.y = (w2.z & 0xBFFFu) | ((w2.w & 0xBFFFu) << 16);
      cB.z = (w3.x & 0xBFFFu) | ((w3.y & 0xBFFFu) << 16);
      cB.w = (w3.z & 0xBFFFu) | ((w3.w & 0xBFFFu) << 16);
      const int rsw = row2 & 7;
      const int ub = 8 * wv + 2 * q;
      *(uint4v*)&h_lds[row2][((ub)     ^ rsw) * 8] = hA;
      *(uint4v*)&h_lds[row2][((ub + 1) ^ rsw) * 8] = hB;
      *(uint4v*)&c_lds[row2][((ub)     ^ rsw) * 8] = cA;
      *(uint4v*)&c_lds[row2][((ub + 1) ^ rsw) * 8] = cB;
    }
    LGKM_BARRIER();                                    // barrier 1

    // ===== phase 2: slow VMEM issues + GEMM ================================
    if (T > 0)
      __builtin_nontemporal_store(ohold,
          &out[((size_t)(BASE + cm) * kT + (T - 1)) * kH + colg]);
    if (T + 1 < kT) {   // stage x[T+1] (read by next iteration's phase 1)
      uint4v xv;
      xv.x = (unsigned)f2bf(xar.x) | ((unsigned)f2bf(xar.y) << 16);
      xv.y = (unsigned)f2bf(xar.z) | ((unsigned)f2bf(xar.w) << 16);
      xv.z = (unsigned)f2bf(xbr.x) | ((unsigned)f2bf(xbr.y) << 16);
      xv.w = (unsigned)f2bf(xbr.z) | ((unsigned)f2bf(xbr.w) << 16);
      *(uint4v*)&XL[r][(ch ^ rs) * 8] = xv;
    }
    if (T + 2 < kT) {   // prefetch x[T+2] (HBM; completes during GEMM+cell)
      const float* xs = inp + ((size_t)(BASE + r) * kT + (T + 2)) * kD + ch * 8;
      xar = *(const float4*)xs; xbr = *(const float4*)(xs + 4);
    }
    float tdn = (T + 1 < kT) ? tdel[(size_t)(BASE + cm) * kT + (T + 1)] : 0.0f;
    if (T > 0) {
      f32x4 a0 = xacc, a1 = {0.f, 0.f, 0.f, 0.f};
      #pragma unroll
      for (int kt = 0; kt < 8; ++kt) {
        short8v av = *(const short8v*)&h_lds[lm][((kt * 4 + lg) ^ (lm & 7)) * 8];
        a0 = __builtin_amdgcn_mfma_f32_16x16x32_bf16(av, bU[kt], a0, 0, 0, 0);
      }
      #pragma unroll
      for (int kt = 8; kt < 16; ++kt) {
        short8v av = *(const short8v*)&h_lds[lm][((kt * 4 + lg) ^ (lm & 7)) * 8];
        a1 = __builtin_amdgcn_mfma_f32_16x16x32_bf16(av, bU[kt], a1, 0, 0, 0);
      }
      f32x4 aw = {0.f, 0.f, 0.f, 0.f};
      #pragma unroll
      for (int kt = 0; kt < 4; ++kt) {
        short8v av = *(const short8v*)&c_lds[lm][((kq * 16 + kt * 4 + lg) ^ (lm & 7)) * 8];
        aw = __builtin_amdgcn_mfma_f32_16x16x32_bf16(av, bWd[kt], aw, 0, 0, 0);
      }
      #pragma unroll
      for (int j = 0; j < 4; ++j) {
        g5[wv][ln * 5 + j] = a0[j] + a1[j];
        s5[wv][ln * 5 + j] = aw[j];
      }
    } else {
      #pragma unroll
      for (int j = 0; j < 4; ++j) g5[wv][ln * 5 + j] = xacc[j];
    }
    LGKM_BARRIER();                                    // barrier 2

    // ===== phase 3: cell -> tagged hc store -> subflag -> spec for other ====
    {
      float g0 = g5[0 + chf][lidx * 5 + jr];
      float g1 = g5[2 + chf][lidx * 5 + jr];
      float g2 = g5[4 + chf][lidx * 5 + jr];
      float g3 = g5[6 + chf][lidx * 5 + jr];
      float sw = 0.f;
      if (T > 0) {
        #pragma unroll
        for (int q2 = 0; q2 < 4; ++q2) sw += s5[2 * q2 + chf][lidx * 5 + jr];
      }
      float csv  = ftanh(sw);
      float cadj = (ckeep - csv) + csv / __logf(2.71828182845904523536f + tdvr);
      float gi = fsig(g0), gf = fsig(g1), gg = ftanh(g2), go = fsig(g3);
      float cnew = fmaf(gf, cadj, gi * gg);
      float tcn  = ftanh(cnew);            // = c_out
      float hout = ftanh(go * tcn);        // = tanh(o * tanh(c_new))
      ckeep = tcn;
      ohold = hout;
      unsigned wout = ((unsigned)f2bf(hout) << 16) | (unsigned)f2bf(tcn)
                    | (((unsigned)(T >> 1) & 1u) << 14);
      unsigned* dst = hc + ((size_t)(T & 1) * kB + BASE + cm) * kH + colg;
      asm volatile("global_store_dword %0, %1, off sc1"
                   :: "v"(dst), "v"(wout) : "memory");
      if (ln == 0) {   // this wave's data issued -> publish its sub-flag
        unsigned* fdst = flags + (size_t)((bid * 2 + SID) * 8 + wv) * 32;
        unsigned fv = (unsigned)(T + 1);
        asm volatile("global_store_dword %0, %1, off sc1"
                     :: "v"(fdst), "v"(fv) : "memory");
      }
    }
    if (OT >= 0) {   // speculative load for the OTHER stream's step OT
      const unsigned* srco = hc + ((size_t)(OT & 1) * kB + OBASE + row2) * kH
                                + 64 * wv + 16 * q;
      asm volatile(
        "global_load_dwordx4 %0, %4, off sc1\n\t"
        "global_load_dwordx4 %1, %4, off offset:16 sc1\n\t"
        "global_load_dwordx4 %2, %4, off offset:32 sc1\n\t"
        "global_load_dwordx4 %3, %4, off offset:48 sc1"
        : "=&v"(n0), "=&v"(n1), "=&v"(n2), "=&v"(n3)
        : "v"(srco) : "memory");
    }
    tdvr = tdn;
    LGKM_BARRIER();                                    // barrier 3
  };

  // ---------------- prologue: stage x[0], prefetch x[1], tdel[0] ------------
  float td0, td1;
  {
    const float* xs0 = inp + ((size_t)(base0 + r) * kT + 0) * kD + ch * 8;
    float4 a = *(const float4*)xs0, b = *(const float4*)(xs0 + 4);
    uint4v xv;
    xv.x = (unsigned)f2bf(a.x) | ((unsigned)f2bf(a.y) << 16);
    xv.y = (unsigned)f2bf(a.z) | ((unsigned)f2bf(a.w) << 16);
    xv.z = (unsigned)f2bf(b.x) | ((unsigned)f2bf(b.y) << 16);
    xv.w = (unsigned)f2bf(b.z) | ((unsigned)f2bf(b.w) << 16);
    *(uint4v*)&x_lds[0][r][(ch ^ rs) * 8] = xv;
    const float* xs1 = inp + ((size_t)(base1 + r) * kT + 0) * kD + ch * 8;
    a = *(const float4*)xs1; b = *(const float4*)(xs1 + 4);
    xv.x = (unsigned)f2bf(a.x) | ((unsigned)f2bf(a.y) << 16);
    xv.y = (unsigned)f2bf(a.z) | ((unsigned)f2bf(a.w) << 16);
    xv.z = (unsigned)f2bf(b.x) | ((unsigned)f2bf(b.y) << 16);
    xv.w = (unsigned)f2bf(b.z) | ((unsigned)f2bf(b.w) << 16);
    *(uint4v*)&x_lds[1][r][(ch ^ rs) * 8] = xv;
  }
  {
    const float* xs0 = inp + ((size_t)(base0 + r) * kT + 1) * kD + ch * 8;
    xa0 = *(const float4*)xs0; xb0 = *(const float4*)(xs0 + 4);
    const float* xs1 = inp + ((size_t)(base1 + r) * kT + 1) * kD + ch * 8;
    xa1 = *(const float4*)xs1; xb1 = *(const float4*)(xs1 + 4);
  }
  td0 = tdel[(size_t)(base0 + cm) * kT + 0];
  td1 = tdel[(size_t)(base1 + cm) * kT + 0];
  __syncthreads();

  // ---------------- main loop: two interleaved half-steps per iteration -----
  for (int t = 0; t < kT; ++t) {
    // half A (stream 0, step t); issues spec for stream 1's hc[t-1]
    half(t, 0, base0, base1, (t > 0) ? t - 1 : -1, x_lds[0],
         ck0, oh0, td0, xa0, xb0, wA0, wA1, wA2, wA3, wB0, wB1, wB2, wB3);
    // half B (stream 1, step t); issues spec for stream 0's hc[t]
    half(t, 1, base1, base0, (t + 1 < kT) ? t : -1, x_lds[1],
         ck1, oh1, td1, xa1, xb1, wB0, wB1, wB2, wB3, wA0, wA1, wA2, wA3);
  }

  // ---------------- epilogue: t = kT-1 outputs ------------------------------
  out[((size_t)(base0 + cm) * kT + (kT - 1)) * kH + colg] = oh0;
  out[HID + (size_t)(base0 + cm) * kH + colg] = oh0;                    // h_t
  out[HID + (size_t)kB * kH + (size_t)(base0 + cm) * kH + colg] = ck0;  // c_t
  out[((size_t)(base1 + cm) * kT + (kT - 1)) * kH + colg] = oh1;
  out[HID + (size_t)(base1 + cm) * kH + colg] = oh1;                    // h_t
  out[HID + (size_t)kB * kH + (size_t)(base1 + cm) * kH + colg] = ck1;  // c_t
}

extern "C" void kernel_launch(void* const* d_in, const int* in_sizes, int n_in,
                              void* d_out, int out_size, void* d_ws, size_t ws_size,
                              hipStream_t stream)
{
  const float* inp  = (const float*)d_in[0];
  const float* td   = (const float*)d_in[1];
  const float* Wd   = (const float*)d_in[2];
  const float* W    = (const float*)d_in[3];
  const float* U    = (const float*)d_in[4];
  const float* bias = (const float*)d_in[5];
  float* out = (float*)d_out;

  // ws: hc[2][64][512] u32 (256 KB) | subflags 32*2*8*32 u32 (64 KB).
  // hc memset 0xFF: tag bit14=1 everywhere -> t=1 (epoch 0) rejects stale
  // data incl. the harness 0xAA poison. flags memset 0.
  unsigned* hc    = (unsigned*)d_ws;
  unsigned* flags = hc + (size_t)2 * kB * kH;

  (void)hipMemsetAsync(hc, 0xFF, (size_t)2 * kB * kH * sizeof(unsigned), stream);
  (void)hipMemsetAsync(flags, 0, (size_t)NBLK * 2 * 8 * 32 * sizeof(unsigned), stream);
  mtsltm_kernel<<<dim3(NBLK), dim3(NTHR), 0, stream>>>(inp, td, Wd, W, U, bias,
                                                       out, hc, flags);
}

// Round 14
// 1532.703 us; speedup vs baseline: 2.7505x; 2.7505x over previous
//
#include <hip/hip_runtime.h>

// ---------------------------------------------------------------------------
// MTSLTM (time-aware LSTM), B=64 T=512 D=256 H=512 — round 14.
// Persistent kernel: 64 blocks x 512 threads (8 waves), 1 block/CU.
// Grid: 4 batch-groups (16 batches, bg=bid&3) x 16 col-slices (32 h-cols).
// Exchange: agent-scope sc1, SELF-VALIDATING tagged words ONLY (no flags):
//   word = (h_bf16<<16) | c_bf16 | ((t>>1)&1)<<14   (bit14 free: tanh range)
//   Skew between blocks is bounded to +-1 step by the mutual data dependency
//   (a producer cannot advance 2 steps without this block's output), so a
//   1-bit epoch distinguishes every reachable buffer state. Cross-launch
//   staleness killed by per-launch memset(0xFF) (tag=1, rejected at t=1).
// vs r12 (1677us):
//   * barrier C removed (A of the next step already orders g5/s5 reuse);
//     x_lds double-buffered to close its hazard window. 2 barriers/step.
//   * flag stores + flag-poll fallback removed; spec miss -> s_sleep-paced
//     bounded direct reload (rare: spec load is issued after an ~80cy LDS
//     stage so it reaches L3 after the producers' stores become visible).
//   * out[] plain store (fast L2 ack) so ph1's FIFO vmcnt(0) never waits HBM.
// ---------------------------------------------------------------------------

constexpr int kB = 64, kT = 512, kD = 256, kH = 512, kG = 2048;
constexpr int NBLK = 64, NTHR = 512;

typedef __attribute__((ext_vector_type(8))) short short8v;   // 8 bf16
typedef __attribute__((ext_vector_type(4))) float f32x4;
typedef __attribute__((ext_vector_type(4))) unsigned int uint4v;

__device__ __forceinline__ float fsig(float x)  { return 1.0f / (1.0f + __expf(-x)); }
__device__ __forceinline__ float ftanh(float x) { return 2.0f / (1.0f + __expf(-2.0f * x)) - 1.0f; }
__device__ __forceinline__ unsigned short f2bf(float f) {    // RNE f32->bf16
  unsigned u = __float_as_uint(f);
  return (unsigned short)((u + 0x7FFFu + ((u >> 16) & 1u)) >> 16);
}

#define LGKM_BARRIER() asm volatile("s_waitcnt lgkmcnt(0)\n\ts_barrier" ::: "memory")

__global__ __launch_bounds__(NTHR, 1) void mtsltm_kernel(
    const float* __restrict__ inp, const float* __restrict__ tdel,
    const float* __restrict__ Wd,  const float* __restrict__ W,
    const float* __restrict__ U,   const float* __restrict__ bias,
    float* __restrict__ out, unsigned* __restrict__ hc)
{
  // 68.5 KB LDS. h/c/x XOR-swizzled in 16B units (unit' = unit ^ (row&7)).
  __shared__ __align__(16) unsigned short h_lds[16][512];     // 16 KB
  __shared__ __align__(16) unsigned short c_lds[16][512];     // 16 KB
  __shared__ __align__(16) unsigned short x_lds[2][16][256];  // 16 KB (dbuf)
  __shared__ float g5[8][320];   // gate tiles, stride-5 (conflict-free)
  __shared__ float s5[8][320];   // Wd partials, stride-5

  const int tid = threadIdx.x, bid = blockIdx.x;
  const int bg = bid & 3;          // batch group (16-block exchange group)
  const int cs = bid >> 2;         // col slice [0,16): h-cols cs*32..cs*32+32
  const int wv = tid >> 6, ln = tid & 63;
  const int lm = ln & 15, lg = ln >> 4;   // MFMA lane decomposition

  // ---------------- one-time: weights -> VGPRs (bf16 B-fragments) -----------
  const int gcol = (wv >> 1) * kH + cs * 32 + (wv & 1) * 16 + lm;
  short8v bU[16];                                   // U[512][gcol]
  #pragma unroll
  for (int kt = 0; kt < 16; ++kt) {
    short8v v;
    #pragma unroll
    for (int e = 0; e < 8; ++e)
      v[e] = (short)f2bf(U[(size_t)(kt * 32 + lg * 8 + e) * kG + gcol]);
    bU[kt] = v;
  }
  short8v bX[8];                                    // W[256][gcol]
  #pragma unroll
  for (int kt = 0; kt < 8; ++kt) {
    short8v v;
    #pragma unroll
    for (int e = 0; e < 8; ++e)
      v[e] = (short)f2bf(W[(size_t)(kt * 32 + lg * 8 + e) * kG + gcol]);
    bX[kt] = v;
  }
  const int kq = wv >> 1, ns = wv & 1;   // Wd: k-quarter kq, n-tile ns
  short8v bWd[4];
  #pragma unroll
  for (int kt = 0; kt < 4; ++kt) {
    short8v v;
    #pragma unroll
    for (int e = 0; e < 8; ++e)
      v[e] = (short)f2bf(Wd[(size_t)(kq * 128 + kt * 32 + lg * 8 + e) * kH
                            + cs * 32 + ns * 16 + lm]);
    bWd[kt] = v;
  }
  const float bias_r = bias[gcol];

  // ---------------- identities ----------------
  const int r = tid & 15, ch = tid >> 4, rs = r & 7;   // x staging
  const int bgl_r = bg * 16 + r;
  const int row2 = ln >> 2, q = ln & 3;                // hc staging (per wave)
  const int cm = tid >> 5, cj = tid & 31;              // cell: batch cm, col cj
  const int lidx = ((cm >> 2) << 4) | (cj & 15), jr = cm & 3, chf = cj >> 4;
  const size_t bglc = (size_t)bg * 16 + cm;
  const int colg = cs * 32 + cj;
  float c_keep = 0.0f;                                 // exact f32 cell carry
  float o_hold = 0.0f;                                 // deferred out value
  const size_t HID = (size_t)kB * kT * kH;

  auto xgemm = [&](int par) -> f32x4 {   // x[t]-part of gates (+bias)
    f32x4 a = {bias_r, bias_r, bias_r, bias_r};
    #pragma unroll
    for (int kt = 0; kt < 8; ++kt) {
      short8v av = *(const short8v*)&x_lds[par][lm][((kt * 4 + lg) ^ (lm & 7)) * 8];
      a = __builtin_amdgcn_mfma_f32_16x16x32_bf16(av, bX[kt], a, 0, 0, 0);
    }
    return a;
  };

  // ---------------- prologue: stage x[0], prefetch x[1], tdel[0] ------------
  {
    const float* xs = inp + ((size_t)bgl_r * kT + 0) * kD + ch * 8;
    float4 a = *(const float4*)xs, b = *(const float4*)(xs + 4);
    uint4v xv;
    xv.x = (unsigned)f2bf(a.x) | ((unsigned)f2bf(a.y) << 16);
    xv.y = (unsigned)f2bf(a.z) | ((unsigned)f2bf(a.w) << 16);
    xv.z = (unsigned)f2bf(b.x) | ((unsigned)f2bf(b.y) << 16);
    xv.w = (unsigned)f2bf(b.z) | ((unsigned)f2bf(b.w) << 16);
    *(uint4v*)&x_lds[0][r][(ch ^ rs) * 8] = xv;
  }
  float4 xa, xb;
  {
    const float* xs = inp + ((size_t)bgl_r * kT + 1) * kD + ch * 8;
    xa = *(const float4*)xs; xb = *(const float4*)(xs + 4);
  }
  float tdv = tdel[bglc * kT + 0];
  __syncthreads();

  for (int t = 0; t < kT; ++t) {
    // ============ phase 1: x-stage -> spec hc load -> xgemm -> validate =====
    if (t + 1 < kT) {   // stage x[t+1] into the other buffer (regs from ph2(t-1))
      uint4v xv;
      xv.x = (unsigned)f2bf(xa.x) | ((unsigned)f2bf(xa.y) << 16);
      xv.y = (unsigned)f2bf(xa.z) | ((unsigned)f2bf(xa.w) << 16);
      xv.z = (unsigned)f2bf(xb.x) | ((unsigned)f2bf(xb.y) << 16);
      xv.w = (unsigned)f2bf(xb.z) | ((unsigned)f2bf(xb.w) << 16);
      *(uint4v*)&x_lds[(t + 1) & 1][r][(ch ^ rs) * 8] = xv;
    }
    uint4v w0, w1, w2, w3;
    const unsigned* src = nullptr;
    if (t > 0) {
      // speculative tagged-data load (issued ~80cy into the step -> arrives
      // at L3 after the producers' stores become visible in lockstep)
      src = hc + ((size_t)((t - 1) & 1) * kB + bg * 16 + row2) * kH
               + 64 * wv + 16 * q;
      asm volatile(
        "global_load_dwordx4 %0, %4, off sc1\n\t"
        "global_load_dwordx4 %1, %4, off offset:16 sc1\n\t"
        "global_load_dwordx4 %2, %4, off offset:32 sc1\n\t"
        "global_load_dwordx4 %3, %4, off offset:48 sc1"
        : "=&v"(w0), "=&v"(w1), "=&v"(w2), "=&v"(w3)
        : "v"(src) : "memory");
    }
    f32x4 xacc = xgemm(t & 1);   // in the spec-load latency shadow
    if (t > 0) {
      asm volatile("s_waitcnt vmcnt(0)" ::: "memory");
      __builtin_amdgcn_sched_barrier(0);
      const unsigned ep = (((unsigned)(t - 1) >> 1) & 1u) << 14;
      unsigned bad = (w0.x ^ ep) | (w0.y ^ ep) | (w0.z ^ ep) | (w0.w ^ ep)
                   | (w1.x ^ ep) | (w1.y ^ ep) | (w1.z ^ ep) | (w1.w ^ ep)
                   | (w2.x ^ ep) | (w2.y ^ ep) | (w2.z ^ ep) | (w2.w ^ ep)
                   | (w3.x ^ ep) | (w3.y ^ ep) | (w3.z ^ ep) | (w3.w ^ ep);
      int vt = 0;
      while (!__all((bad & 0x4000u) == 0u)) {
        if (++vt > (1 << 16)) break;   // safety valve: fail loud, not hung
        asm volatile("s_sleep 1" ::: "memory");
        asm volatile(
          "global_load_dwordx4 %0, %4, off sc1\n\t"
          "global_load_dwordx4 %1, %4, off offset:16 sc1\n\t"
          "global_load_dwordx4 %2, %4, off offset:32 sc1\n\t"
          "global_load_dwordx4 %3, %4, off offset:48 sc1\n\t"
          "s_waitcnt vmcnt(0)"
          : "=&v"(w0), "=&v"(w1), "=&v"(w2), "=&v"(w3)
          : "v"(src) : "memory");
        __builtin_amdgcn_sched_barrier(0);
        bad = (w0.x ^ ep) | (w0.y ^ ep) | (w0.z ^ ep) | (w0.w ^ ep)
            | (w1.x ^ ep) | (w1.y ^ ep) | (w1.z ^ ep) | (w1.w ^ ep)
            | (w2.x ^ ep) | (w2.y ^ ep) | (w2.z ^ ep) | (w2.w ^ ep)
            | (w3.x ^ ep) | (w3.y ^ ep) | (w3.z ^ ep) | (w3.w ^ ep);
      }
      // unpack: word = (h<<16) | c (bit14 = epoch tag, masked off)
      uint4v hA, hB, cA, cB;
      hA.x = (w0.x >> 16) | (w0.y & 0xFFFF0000u);
      hA.y = (w0.z >> 16) | (w0.w & 0xFFFF0000u);
      hA.z = (w1.x >> 16) | (w1.y & 0xFFFF0000u);
      hA.w = (w1.z >> 16) | (w1.w & 0xFFFF0000u);
      hB.x = (w2.x >> 16) | (w2.y & 0xFFFF0000u);
      hB.y = (w2.z >> 16) | (w2.w & 0xFFFF0000u);
      hB.z = (w3.x >> 16) | (w3.y & 0xFFFF0000u);
      hB.w = (w3.z >> 16) | (w3.w & 0xFFFF0000u);
      cA.x = (w0.x & 0xBFFFu) | ((w0.y & 0xBFFFu) << 16);
      cA.y = (w0.z & 0xBFFFu) | ((w0.w & 0xBFFFu) << 16);
      cA.z = (w1.x & 0xBFFFu) | ((w1.y & 0xBFFFu) << 16);
      cA.w = (w1.z & 0xBFFFu) | ((w1.w & 0xBFFFu) << 16);
      cB.x = (w2.x & 0xBFFFu) | ((w2.y & 0xBFFFu) << 16);
      cB.y = (w2.z & 0xBFFFu) | ((w2.w & 0xBFFFu) << 16);
      cB.z = (w3.x & 0xBFFFu) | ((w3.y & 0xBFFFu) << 16);
      cB.w = (w3.z & 0xBFFFu) | ((w3.w & 0xBFFFu) << 16);
      const int rsw = row2 & 7;
      const int ub = 8 * wv + 2 * q;
      *(uint4v*)&h_lds[row2][((ub)     ^ rsw) * 8] = hA;
      *(uint4v*)&h_lds[row2][((ub + 1) ^ rsw) * 8] = hB;
      *(uint4v*)&c_lds[row2][((ub)     ^ rsw) * 8] = cA;
      *(uint4v*)&c_lds[row2][((ub + 1) ^ rsw) * 8] = cB;
    }
    LGKM_BARRIER();                                    // barrier A

    // ============ phase 2: slow VMEM issues + GEMM ==========================
    if (t > 0)   // plain store: L2 ack, never holds a later vmcnt(0) long
      out[(bglc * kT + (t - 1)) * kH + colg] = o_hold;
    if (t + 2 < kT) {   // prefetch x[t+2] (HBM; completes during GEMM+cell)
      const float* xs = inp + ((size_t)bgl_r * kT + (t + 2)) * kD + ch * 8;
      xa = *(const float4*)xs; xb = *(const float4*)(xs + 4);
    }
    float tdn = (t + 1 < kT) ? tdel[bglc * kT + (t + 1)] : 0.0f;
    if (t > 0) {
      f32x4 a0 = xacc, a1 = {0.f, 0.f, 0.f, 0.f};
      #pragma unroll
      for (int kt = 0; kt < 8; ++kt) {
        short8v av = *(const short8v*)&h_lds[lm][((kt * 4 + lg) ^ (lm & 7)) * 8];
        a0 = __builtin_amdgcn_mfma_f32_16x16x32_bf16(av, bU[kt], a0, 0, 0, 0);
      }
      #pragma unroll
      for (int kt = 8; kt < 16; ++kt) {
        short8v av = *(const short8v*)&h_lds[lm][((kt * 4 + lg) ^ (lm & 7)) * 8];
        a1 = __builtin_amdgcn_mfma_f32_16x16x32_bf16(av, bU[kt], a1, 0, 0, 0);
      }
      f32x4 aw = {0.f, 0.f, 0.f, 0.f};
      #pragma unroll
      for (int kt = 0; kt < 4; ++kt) {
        short8v av = *(const short8v*)&c_lds[lm][((kq * 16 + kt * 4 + lg) ^ (lm & 7)) * 8];
        aw = __builtin_amdgcn_mfma_f32_16x16x32_bf16(av, bWd[kt], aw, 0, 0, 0);
      }
      #pragma unroll
      for (int j = 0; j < 4; ++j) {
        g5[wv][ln * 5 + j] = a0[j] + a1[j];
        s5[wv][ln * 5 + j] = aw[j];
      }
    } else {
      #pragma unroll
      for (int j = 0; j < 4; ++j) g5[wv][ln * 5 + j] = xacc[j];
    }
    LGKM_BARRIER();                                    // barrier B

    // ============ phase 3: cell -> tagged hc store (no flag, no barrier) ====
    {
      float g0 = g5[0 + chf][lidx * 5 + jr];
      float g1 = g5[2 + chf][lidx * 5 + jr];
      float g2 = g5[4 + chf][lidx * 5 + jr];
      float g3 = g5[6 + chf][lidx * 5 + jr];
      float sw = 0.f;
      if (t > 0) {
        #pragma unroll
        for (int q2 = 0; q2 < 4; ++q2) sw += s5[2 * q2 + chf][lidx * 5 + jr];
      }
      float csv  = ftanh(sw);
      float cadj = (c_keep - csv) + csv / __logf(2.71828182845904523536f + tdv);
      float gi = fsig(g0), gf = fsig(g1), gg = ftanh(g2), go = fsig(g3);
      float cnew = fmaf(gf, cadj, gi * gg);
      float tcn  = ftanh(cnew);            // = c_out
      float hout = ftanh(go * tcn);        // = tanh(o * tanh(c_new))
      c_keep = tcn;
      o_hold = hout;
      unsigned wout = ((unsigned)f2bf(hout) << 16) | (unsigned)f2bf(tcn)
                    | (((unsigned)(t >> 1) & 1u) << 14);
      unsigned* dst = hc + ((size_t)(t & 1) * kB + bglc) * kH + colg;
      asm volatile("global_store_dword %0, %1, off sc1"
                   :: "v"(dst), "v"(wout) : "memory");
    }
    tdv = tdn;
    // no barrier C: barrier A of the next step orders g5/s5 reuse; x_lds is
    // double-buffered; hc readers self-validate via the epoch tag.
  }

  // ---------------- epilogue: t = kT-1 outputs ------------------------------
  out[(bglc * kT + (kT - 1)) * kH + colg] = o_hold;
  out[HID + bglc * kH + colg] = o_hold;                      // h_t
  out[HID + (size_t)kB * kH + bglc * kH + colg] = c_keep;    // c_t
}

extern "C" void kernel_launch(void* const* d_in, const int* in_sizes, int n_in,
                              void* d_out, int out_size, void* d_ws, size_t ws_size,
                              hipStream_t stream)
{
  const float* inp  = (const float*)d_in[0];
  const float* td   = (const float*)d_in[1];
  const float* Wd   = (const float*)d_in[2];
  const float* W    = (const float*)d_in[3];
  const float* U    = (const float*)d_in[4];
  const float* bias = (const float*)d_in[5];
  float* out = (float*)d_out;

  // ws: hc[2][64][512] u32 (256 KB). Memset 0xFF each launch: tag bit14=1
  // everywhere -> t=1 (epoch 0) rejects any stale/poisoned data.
  unsigned* hc = (unsigned*)d_ws;
  (void)hipMemsetAsync(hc, 0xFF, (size_t)2 * kB * kH * sizeof(unsigned), stream);
  mtsltm_kernel<<<dim3(NBLK), dim3(NTHR), 0, stream>>>(inp, td, Wd, W, U, bias,
                                                       out, hc);
}